// Round 2
// baseline (333.310 us; speedup 1.0000x reference)
//
#include <hip/hip_runtime.h>
#include <hip/hip_bf16.h>
#include <stdint.h>

#define B_ 256
#define T_ 256
#define D_ 128
#define H_ 256
#define LN_EPS 1e-5

// -------- K1: h1[r][h] = LN_H( x[r][:] . W1[h][:] + b1[h] ), fp64 out --------
// block: 64 rows x 256 cols (full H), 256 threads, thread tile 8x8
__global__ __launch_bounds__(256, 2) void k1_gemm_ln(
    const float* __restrict__ x, const float* __restrict__ W1,
    const float* __restrict__ b1, const float* __restrict__ g1, const float* __restrict__ be1,
    double* __restrict__ h1, int row0)
{
  __shared__ double As[16][64];   // [k][row]  8 KB
  __shared__ double Bs[16][256];  // [k][col] 32 KB
  const int tid = threadIdx.x;
  const int tx = tid & 31, ty = tid >> 5;
  const int orow = blockIdx.x * 64;     // chunk-local row base
  const int grow = row0 + orow;         // global row base into x

  double acc[8][8];
  #pragma unroll
  for (int i = 0; i < 8; ++i)
    #pragma unroll
    for (int j = 0; j < 8; ++j) acc[i][j] = 0.0;

  for (int kt = 0; kt < 128; kt += 16) {
    __syncthreads();
    { // stage A: 64 rows x 16 k (fp32 -> fp64, exact)
      const int row = tid >> 2, ko = (tid & 3) * 4;
      const float4 f = *(const float4*)(x + (size_t)(grow + row) * 128 + kt + ko);
      As[ko+0][row] = (double)f.x; As[ko+1][row] = (double)f.y;
      As[ko+2][row] = (double)f.z; As[ko+3][row] = (double)f.w;
    }
    { // stage B: 16 k x 256 cols from W1[col][k] (row-major [H][D])
      const float* src = W1 + (size_t)tid * 128 + kt;
      #pragma unroll
      for (int j = 0; j < 4; ++j) {
        const float4 f = *(const float4*)(src + j*4);
        Bs[j*4+0][tid] = (double)f.x; Bs[j*4+1][tid] = (double)f.y;
        Bs[j*4+2][tid] = (double)f.z; Bs[j*4+3][tid] = (double)f.w;
      }
    }
    __syncthreads();
    #pragma unroll 2
    for (int k = 0; k < 16; ++k) {
      double a[8], b[8];
      #pragma unroll
      for (int j = 0; j < 4; ++j) {
        const double2 t2 = *(const double2*)&As[k][ty*8 + j*2];
        a[j*2] = t2.x; a[j*2+1] = t2.y;
      }
      #pragma unroll
      for (int c = 0; c < 4; ++c) {
        const double2 t2 = *(const double2*)&Bs[k][c*64 + tx*2];
        b[c*2] = t2.x; b[c*2+1] = t2.y;
      }
      #pragma unroll
      for (int i = 0; i < 8; ++i)
        #pragma unroll
        for (int j = 0; j < 8; ++j)
          acc[i][j] = fma(a[i], b[j], acc[i][j]);
    }
  }

  // bias + LayerNorm over H=256 (row spread across 32 lanes x 8 vals)
  double gg[8], ee[8];
  #pragma unroll
  for (int j = 0; j < 8; ++j) {
    const int col = (j >> 1)*64 + tx*2 + (j & 1);
    const double bb = (double)b1[col];
    gg[j] = (double)g1[col]; ee[j] = (double)be1[col];
    #pragma unroll
    for (int i = 0; i < 8; ++i) acc[i][j] += bb;
  }
  #pragma unroll
  for (int i = 0; i < 8; ++i) {
    double s = 0.0, q = 0.0;
    #pragma unroll
    for (int j = 0; j < 8; ++j) { s += acc[i][j]; q += acc[i][j]*acc[i][j]; }
    #pragma unroll
    for (int m = 16; m >= 1; m >>= 1) { s += __shfl_xor(s, m, 64); q += __shfl_xor(q, m, 64); }
    const double mean = s * (1.0/256.0);
    const double var  = q * (1.0/256.0) - mean*mean;
    const double rstd = 1.0 / sqrt(var + LN_EPS);
    const int r = orow + ty*8 + i;
    #pragma unroll
    for (int c = 0; c < 4; ++c) {
      double2 o;
      o.x = (acc[i][c*2+0] - mean) * rstd * gg[c*2+0] + ee[c*2+0];
      o.y = (acc[i][c*2+1] - mean) * rstd * gg[c*2+1] + ee[c*2+1];
      *(double2*)&h1[(size_t)r*256 + c*64 + tx*2] = o;
    }
  }
}

// -------- K2: LIF over T per (b,h) channel; spikes as bytes --------
__global__ __launch_bounds__(256) void k2_lif(
    const double* __restrict__ h1, uint8_t* __restrict__ s1)
{
  const int ci = blockIdx.x * 256 + threadIdx.x;  // < Bc*H
  const int b = ci >> 8, h = ci & 255;
  const double* p = h1 + (size_t)b * (T_*H_) + h;
  uint8_t* qp = s1 + (size_t)b * (T_*H_) + h;
  double v = 0.0;
  #pragma unroll 8
  for (int t = 0; t < T_; ++t) {
    const double xv = p[(size_t)t * H_];
    const double hm = v + (xv - v) * 0.5;   // charge, TAU=2 (exact in fp64)
    const bool s = (hm >= 1.0);             // fire at V_TH=1
    v = s ? 0.0 : hm;                       // hard reset
    qp[(size_t)t * H_] = s ? (uint8_t)1 : (uint8_t)0;
  }
}

// -------- K3: h2[r][d] = LN_D( s1[r][:] . W2[d][:] + b2[d] ), fp64 out --------
__global__ __launch_bounds__(256, 2) void k3_gemm_ln(
    const uint8_t* __restrict__ s1, const float* __restrict__ W2,
    const float* __restrict__ b2, const float* __restrict__ g2, const float* __restrict__ be2,
    double* __restrict__ h2)
{
  __shared__ double As[32][64];   // [k][row] 16 KB (spikes as 0.0/1.0)
  __shared__ double Bs[32][128];  // [k][col] 32 KB
  const int tid = threadIdx.x;
  const int tx = tid & 31, ty = tid >> 5;
  const int orow = blockIdx.x * 64;

  double acc[8][4];
  #pragma unroll
  for (int i = 0; i < 8; ++i)
    #pragma unroll
    for (int j = 0; j < 4; ++j) acc[i][j] = 0.0;

  for (int kt = 0; kt < 256; kt += 32) {
    __syncthreads();
    { // stage A: 64 rows x 32 k spike bytes -> fp64
      const int row = tid >> 2, ko = (tid & 3) * 8;
      const uint2 u = *(const uint2*)(s1 + (size_t)(orow + row) * 256 + kt + ko);
      #pragma unroll
      for (int j = 0; j < 4; ++j) As[ko+j][row]   = (double)((u.x >> (8*j)) & 0xffu);
      #pragma unroll
      for (int j = 0; j < 4; ++j) As[ko+4+j][row] = (double)((u.y >> (8*j)) & 0xffu);
    }
    { // stage B: 32 k x 128 cols from W2[col][k] (row-major [D][H])
      const int col = tid >> 1, k0 = (tid & 1) * 16;
      const float* src = W2 + (size_t)col * 256 + kt + k0;
      #pragma unroll
      for (int j = 0; j < 4; ++j) {
        const float4 f = *(const float4*)(src + j*4);
        Bs[k0+j*4+0][col] = (double)f.x; Bs[k0+j*4+1][col] = (double)f.y;
        Bs[k0+j*4+2][col] = (double)f.z; Bs[k0+j*4+3][col] = (double)f.w;
      }
    }
    __syncthreads();
    #pragma unroll 2
    for (int k = 0; k < 32; ++k) {
      double a[8], b[4];
      #pragma unroll
      for (int j = 0; j < 4; ++j) {
        const double2 t2 = *(const double2*)&As[k][ty*8 + j*2];
        a[j*2] = t2.x; a[j*2+1] = t2.y;
      }
      #pragma unroll
      for (int c = 0; c < 2; ++c) {
        const double2 t2 = *(const double2*)&Bs[k][c*64 + tx*2];
        b[c*2] = t2.x; b[c*2+1] = t2.y;
      }
      #pragma unroll
      for (int i = 0; i < 8; ++i)
        #pragma unroll
        for (int j = 0; j < 4; ++j)
          acc[i][j] = fma(a[i], b[j], acc[i][j]);
    }
  }

  double gg[4], ee[4];
  #pragma unroll
  for (int j = 0; j < 4; ++j) {
    const int col = (j >> 1)*64 + tx*2 + (j & 1);
    const double bb = (double)b2[col];
    gg[j] = (double)g2[col]; ee[j] = (double)be2[col];
    #pragma unroll
    for (int i = 0; i < 8; ++i) acc[i][j] += bb;
  }
  #pragma unroll
  for (int i = 0; i < 8; ++i) {
    double s = 0.0, q = 0.0;
    #pragma unroll
    for (int j = 0; j < 4; ++j) { s += acc[i][j]; q += acc[i][j]*acc[i][j]; }
    #pragma unroll
    for (int m = 16; m >= 1; m >>= 1) { s += __shfl_xor(s, m, 64); q += __shfl_xor(q, m, 64); }
    const double mean = s * (1.0/128.0);
    const double var  = q * (1.0/128.0) - mean*mean;
    const double rstd = 1.0 / sqrt(var + LN_EPS);
    const int r = orow + ty*8 + i;
    #pragma unroll
    for (int c = 0; c < 2; ++c) {
      double2 o;
      o.x = (acc[i][c*2+0] - mean)*rstd*gg[c*2+0] + ee[c*2+0];
      o.y = (acc[i][c*2+1] - mean)*rstd*gg[c*2+1] + ee[c*2+1];
      *(double2*)&h2[(size_t)r*128 + c*64 + tx*2] = o;
    }
  }
}

// -------- K4: LIF over T per (b,d) + residual add, fp32 out --------
__global__ __launch_bounds__(64) void k4_lif_res(
    const double* __restrict__ h2, const float* __restrict__ x,
    float* __restrict__ out, int row0)
{
  const int ci = blockIdx.x * 64 + threadIdx.x;  // < Bc*D
  const int b = ci >> 7, d = ci & 127;
  const double* p = h2 + (size_t)b * (T_*D_) + d;
  const size_t gbase = ((size_t)row0 + (size_t)b * T_) * D_ + d;
  double v = 0.0;
  #pragma unroll 8
  for (int t = 0; t < T_; ++t) {
    const double hv = p[(size_t)t * D_];
    const double hm = v + (hv - v) * 0.5;
    const bool s = (hm >= 1.0);
    v = s ? 0.0 : hm;
    out[gbase + (size_t)t * D_] = x[gbase + (size_t)t * D_] + (s ? 1.0f : 0.0f);
  }
}

extern "C" void kernel_launch(void* const* d_in, const int* in_sizes, int n_in,
                              void* d_out, int out_size, void* d_ws, size_t ws_size,
                              hipStream_t stream)
{
  const float* x   = (const float*)d_in[0];
  const float* W1  = (const float*)d_in[1];
  const float* b1  = (const float*)d_in[2];
  const float* g1  = (const float*)d_in[3];
  const float* be1 = (const float*)d_in[4];
  const float* W2  = (const float*)d_in[5];
  const float* b2  = (const float*)d_in[6];
  const float* g2  = (const float*)d_in[7];
  const float* be2 = (const float*)d_in[8];
  float* out = (float*)d_out;

  // per-batch scratch: h1 fp64 [T][H] + s1 u8 [T][H] + h2 fp64 [T][D]
  const size_t per_b = (size_t)T_*H_*sizeof(double) + (size_t)T_*H_ + (size_t)T_*D_*sizeof(double);
  int Bc = B_;
  while (Bc > 1 && (size_t)Bc * per_b > ws_size) Bc >>= 1;

  double*  h1 = (double*)d_ws;
  uint8_t* s1 = (uint8_t*)d_ws + (size_t)Bc*T_*H_*sizeof(double);
  double*  h2 = (double*)((uint8_t*)d_ws + (size_t)Bc*T_*H_*sizeof(double) + (size_t)Bc*T_*H_);

  const int nchunk = B_ / Bc;
  for (int c = 0; c < nchunk; ++c) {
    const int row0 = c * Bc * T_;   // global (b*T) row offset
    k1_gemm_ln<<<dim3(Bc*4), dim3(256), 0, stream>>>(x, W1, b1, g1, be1, h1, row0);
    k2_lif   <<<dim3(Bc),   dim3(256), 0, stream>>>(h1, s1);
    k3_gemm_ln<<<dim3(Bc*4), dim3(256), 0, stream>>>(s1, W2, b2, g2, be2, h2);
    k4_lif_res<<<dim3(Bc*2), dim3(64),  0, stream>>>(h2, x, out, row0);
  }
}

// Round 4
// 309.948 us; speedup vs baseline: 1.0754x; 1.0754x over previous
//
#include <hip/hip_runtime.h>
#include <hip/hip_bf16.h>
#include <stdint.h>

#define B_ 256
#define T_ 256
#define D_ 128
#define H_ 256
#define LN_EPS 1e-5

typedef double f64x4 __attribute__((ext_vector_type(4)));

// Runtime probe of v_mfma_f64_16x16x4f64's C/D register->element mapping.
// Assumes A: lane l holds A[l&15][l>>4]; B: lane l holds B[l>>4][l&15].
// On success (wave-uniform true): col of every acc reg is l&15, and rowp[r]
// is the row (0..15) held by acc reg r (uniform across each 16-lane group,
// groups partition the 16 rows). On failure the caller must use the
// fallback (covers wrong A/B layout assumptions too: probe output goes
// non-integer / out-of-pattern and validation rejects it).
__device__ __forceinline__ bool probe_f64_mfma_layout(int l16, int lg, int* rowp)
{
  const f64x4 zz = {0.0, 0.0, 0.0, 0.0};
  const double pa_r = (lg == 0) ? (double)l16 : 0.0;  // A[i][0] = i
  const double pb_1 = (lg == 0) ? 1.0 : 0.0;          // B[0][j] = 1
  const f64x4 prow = __builtin_amdgcn_mfma_f64_16x16x4f64(pa_r, pb_1, zz, 0, 0, 0); // D[i][j]=i
  const double pa_1 = (lg == 0) ? 1.0 : 0.0;          // A[i][0] = 1
  const double pb_c = (lg == 0) ? (double)l16 : 0.0;  // B[0][j] = j
  const f64x4 pcol = __builtin_amdgcn_mfma_f64_16x16x4f64(pa_1, pb_c, zz, 0, 0, 0); // D[i][j]=j
  bool ok = true;
  int rm = 0, rp = 0;
  #pragma unroll
  for (int r = 0; r < 4; ++r) {
    const int ri = (int)prow[r];
    const int ci = (int)pcol[r];
    rowp[r] = ri;
    ok = ok && ((double)ri == prow[r]) && (ri >= 0) && (ri < 16);
    ok = ok && ((double)ci == pcol[r]) && (ci == l16);
    rm |= 1 << ri;
    rp |= ri << (4 * r);
  }
  ok = ok && (__popc(rm) == 4);
  #pragma unroll
  for (int m = 1; m <= 8; m <<= 1)          // rowp uniform within 16-lane group
    ok = ok && (__shfl_xor(rp, m, 64) == rp);
  int rmw = rm;                             // groups jointly cover rows 0..15
  rmw |= __shfl_xor(rmw, 16, 64);
  rmw |= __shfl_xor(rmw, 32, 64);
  ok = ok && (rmw == 0xFFFF);
  return __all((int)ok) != 0;
}

// -------- K1: h1[r][h] = LN_H( x[r][:] . W1[h][:] + b1[h] ), fp64 --------
// Block: 64 rows x 256 cols, 4 waves; wave owns a 16-row x 256-col strip.
__global__ __launch_bounds__(256, 2) void k1_gemm_ln(
    const float* __restrict__ x, const float* __restrict__ W1,
    const float* __restrict__ b1, const float* __restrict__ g1, const float* __restrict__ be1,
    double* __restrict__ h1, int row0)
{
  __shared__ double As[16 * 66];    // [k][row]
  __shared__ double Bs[16 * 258];   // [k][col]
  const int tid  = threadIdx.x;
  const int lane = tid & 63, wave = tid >> 6;
  const int l16  = lane & 15, lg = lane >> 4;
  const int orow = blockIdx.x * 64;
  const int grow = row0 + orow;
  const int wrow = wave * 16;

  int rowp[4];
  const bool ok = probe_f64_mfma_layout(l16, lg, rowp);

  // staging (identical for both paths)
  auto stage = [&](int kt) {
    __syncthreads();
    { // A: 64 rows x 16 k (fp32 -> fp64, exact)
      const int row = tid >> 2, ko = (tid & 3) * 4;
      const float4 f = *(const float4*)(x + (size_t)(grow + row) * 128 + kt + ko);
      As[(ko+0)*66 + row] = (double)f.x;
      As[(ko+1)*66 + row] = (double)f.y;
      As[(ko+2)*66 + row] = (double)f.z;
      As[(ko+3)*66 + row] = (double)f.w;
    }
    { // B: Bs[k][col] = W1[col][kt+k]  (W1 row-major [H][D])
      const float* src = W1 + (size_t)tid * 128 + kt;
      #pragma unroll
      for (int j = 0; j < 4; ++j) {
        const float4 f = *(const float4*)(src + j * 4);
        Bs[(j*4+0)*258 + tid] = (double)f.x;
        Bs[(j*4+1)*258 + tid] = (double)f.y;
        Bs[(j*4+2)*258 + tid] = (double)f.z;
        Bs[(j*4+3)*258 + tid] = (double)f.w;
      }
    }
    __syncthreads();
  };

  if (ok) {
    f64x4 acc[16];
    #pragma unroll
    for (int ct = 0; ct < 16; ++ct) acc[ct] = (f64x4){0.0, 0.0, 0.0, 0.0};
    for (int kt = 0; kt < 128; kt += 16) {
      stage(kt);
      #pragma unroll
      for (int ks = 0; ks < 4; ++ks) {
        const int k = ks * 4 + lg;
        const double a = As[k*66 + wrow + l16];
        #pragma unroll
        for (int ct = 0; ct < 16; ++ct) {
          const double b = Bs[k*258 + ct*16 + l16];
          acc[ct] = __builtin_amdgcn_mfma_f64_16x16x4f64(a, b, acc[ct], 0, 0, 0);
        }
      }
    }
    double bb[16];
    #pragma unroll
    for (int ct = 0; ct < 16; ++ct) bb[ct] = (double)b1[ct*16 + l16];
    #pragma unroll
    for (int r = 0; r < 4; ++r) {
      double s = 0.0, q = 0.0;
      #pragma unroll
      for (int ct = 0; ct < 16; ++ct) {
        const double v = acc[ct][r] + bb[ct];
        s += v; q += v * v;
      }
      s += __shfl_xor(s, 1, 64); q += __shfl_xor(q, 1, 64);
      s += __shfl_xor(s, 2, 64); q += __shfl_xor(q, 2, 64);
      s += __shfl_xor(s, 4, 64); q += __shfl_xor(q, 4, 64);
      s += __shfl_xor(s, 8, 64); q += __shfl_xor(q, 8, 64);
      const double mean = s * (1.0/256.0);
      const double var  = q * (1.0/256.0) - mean*mean;
      const double rstd = 1.0 / sqrt(var + LN_EPS);
      const int row = orow + wrow + rowp[r];   // probed row mapping
      #pragma unroll
      for (int ct = 0; ct < 16; ++ct) {
        const int col = ct*16 + l16;
        const double v = acc[ct][r] + bb[ct];
        h1[(size_t)row*256 + col] = (v - mean) * rstd * (double)g1[col] + (double)be1[col];
      }
    }
  } else {
    // fallback: plain fp64 dots; lane owns row wrow+l16, cols lg*64..lg*64+63
    double accv[64];
    #pragma unroll
    for (int c = 0; c < 64; ++c) accv[c] = 0.0;
    for (int kt = 0; kt < 128; kt += 16) {
      stage(kt);
      for (int k = 0; k < 16; ++k) {
        const double a = As[k*66 + wrow + l16];
        #pragma unroll
        for (int c = 0; c < 64; ++c)
          accv[c] = fma(a, Bs[k*258 + lg*64 + c], accv[c]);
      }
    }
    double s = 0.0, q = 0.0;
    #pragma unroll
    for (int c = 0; c < 64; ++c) {
      accv[c] += (double)b1[lg*64 + c];
      s += accv[c]; q += accv[c]*accv[c];
    }
    s += __shfl_xor(s, 16, 64); q += __shfl_xor(q, 16, 64);
    s += __shfl_xor(s, 32, 64); q += __shfl_xor(q, 32, 64);
    const double mean = s * (1.0/256.0);
    const double var  = q * (1.0/256.0) - mean*mean;
    const double rstd = 1.0 / sqrt(var + LN_EPS);
    const int row = orow + wrow + l16;
    #pragma unroll
    for (int c = 0; c < 64; ++c) {
      const int col = lg*64 + c;
      h1[(size_t)row*256 + col] = (accv[c] - mean) * rstd * (double)g1[col] + (double)be1[col];
    }
  }
}

// -------- K2: LIF over T per (b,h) channel; spikes as bytes --------
__global__ __launch_bounds__(256) void k2_lif(
    const double* __restrict__ h1, uint8_t* __restrict__ s1)
{
  const int ci = blockIdx.x * 256 + threadIdx.x;
  const int b = ci >> 8, h = ci & 255;
  const double* p = h1 + (size_t)b * (T_*H_) + h;
  uint8_t* qp = s1 + (size_t)b * (T_*H_) + h;
  double v = 0.0;
  #pragma unroll 8
  for (int t = 0; t < T_; ++t) {
    const double xv = p[(size_t)t * H_];
    const double hm = v + (xv - v) * 0.5;
    const bool s = (hm >= 1.0);
    v = s ? 0.0 : hm;
    qp[(size_t)t * H_] = s ? (uint8_t)1 : (uint8_t)0;
  }
}

// -------- K3: h2[r][d] = LN_D( s1[r][:] . W2[d][:] + b2[d] ), fp64 --------
__global__ __launch_bounds__(256, 2) void k3_gemm_ln(
    const uint8_t* __restrict__ s1, const float* __restrict__ W2,
    const float* __restrict__ b2, const float* __restrict__ g2, const float* __restrict__ be2,
    double* __restrict__ h2)
{
  __shared__ double As[16 * 66];
  __shared__ double Bs[16 * 130];
  const int tid  = threadIdx.x;
  const int lane = tid & 63, wave = tid >> 6;
  const int l16  = lane & 15, lg = lane >> 4;
  const int orow = blockIdx.x * 64;
  const int wrow = wave * 16;

  int rowp[4];
  const bool ok = probe_f64_mfma_layout(l16, lg, rowp);

  auto stage = [&](int kt) {
    __syncthreads();
    { // A: 64 rows x 16 spike bytes -> fp64
      const int row = tid >> 2, ko = (tid & 3) * 4;
      const uint32_t u = *(const uint32_t*)(s1 + (size_t)(orow + row) * 256 + kt + ko);
      As[(ko+0)*66 + row] = (double)( u        & 0xffu);
      As[(ko+1)*66 + row] = (double)((u >> 8)  & 0xffu);
      As[(ko+2)*66 + row] = (double)((u >> 16) & 0xffu);
      As[(ko+3)*66 + row] = (double)((u >> 24) & 0xffu);
    }
    { // B: Bs[k][col] = W2[col][kt+k]  (W2 row-major [D][H])
      const int col = tid >> 1, k0 = (tid & 1) * 8;
      const float* src = W2 + (size_t)col * 256 + kt + k0;
      #pragma unroll
      for (int j = 0; j < 2; ++j) {
        const float4 f = *(const float4*)(src + j * 4);
        Bs[(k0+j*4+0)*130 + col] = (double)f.x;
        Bs[(k0+j*4+1)*130 + col] = (double)f.y;
        Bs[(k0+j*4+2)*130 + col] = (double)f.z;
        Bs[(k0+j*4+3)*130 + col] = (double)f.w;
      }
    }
    __syncthreads();
  };

  if (ok) {
    f64x4 acc[8];
    #pragma unroll
    for (int ct = 0; ct < 8; ++ct) acc[ct] = (f64x4){0.0, 0.0, 0.0, 0.0};
    for (int kt = 0; kt < 256; kt += 16) {
      stage(kt);
      #pragma unroll
      for (int ks = 0; ks < 4; ++ks) {
        const int k = ks * 4 + lg;
        const double a = As[k*66 + wrow + l16];
        #pragma unroll
        for (int ct = 0; ct < 8; ++ct) {
          const double b = Bs[k*130 + ct*16 + l16];
          acc[ct] = __builtin_amdgcn_mfma_f64_16x16x4f64(a, b, acc[ct], 0, 0, 0);
        }
      }
    }
    double bb[8];
    #pragma unroll
    for (int ct = 0; ct < 8; ++ct) bb[ct] = (double)b2[ct*16 + l16];
    #pragma unroll
    for (int r = 0; r < 4; ++r) {
      double s = 0.0, q = 0.0;
      #pragma unroll
      for (int ct = 0; ct < 8; ++ct) {
        const double v = acc[ct][r] + bb[ct];
        s += v; q += v * v;
      }
      s += __shfl_xor(s, 1, 64); q += __shfl_xor(q, 1, 64);
      s += __shfl_xor(s, 2, 64); q += __shfl_xor(q, 2, 64);
      s += __shfl_xor(s, 4, 64); q += __shfl_xor(q, 4, 64);
      s += __shfl_xor(s, 8, 64); q += __shfl_xor(q, 8, 64);
      const double mean = s * (1.0/128.0);
      const double var  = q * (1.0/128.0) - mean*mean;
      const double rstd = 1.0 / sqrt(var + LN_EPS);
      const int row = orow + wrow + rowp[r];
      #pragma unroll
      for (int ct = 0; ct < 8; ++ct) {
        const int col = ct*16 + l16;
        const double v = acc[ct][r] + bb[ct];
        h2[(size_t)row*128 + col] = (v - mean) * rstd * (double)g2[col] + (double)be2[col];
      }
    }
  } else {
    // fallback: lane owns row wrow+l16, cols lg*32..lg*32+31
    double accv[32];
    #pragma unroll
    for (int c = 0; c < 32; ++c) accv[c] = 0.0;
    for (int kt = 0; kt < 256; kt += 16) {
      stage(kt);
      for (int k = 0; k < 16; ++k) {
        const double a = As[k*66 + wrow + l16];
        #pragma unroll
        for (int c = 0; c < 32; ++c)
          accv[c] = fma(a, Bs[k*130 + lg*32 + c], accv[c]);
      }
    }
    double s = 0.0, q = 0.0;
    #pragma unroll
    for (int c = 0; c < 32; ++c) {
      accv[c] += (double)b2[lg*32 + c];
      s += accv[c]; q += accv[c]*accv[c];
    }
    s += __shfl_xor(s, 16, 64); q += __shfl_xor(q, 16, 64);
    s += __shfl_xor(s, 32, 64); q += __shfl_xor(q, 32, 64);
    const double mean = s * (1.0/128.0);
    const double var  = q * (1.0/128.0) - mean*mean;
    const double rstd = 1.0 / sqrt(var + LN_EPS);
    const int row = orow + wrow + l16;
    #pragma unroll
    for (int c = 0; c < 32; ++c) {
      const int col = lg*32 + c;
      h2[(size_t)row*128 + col] = (accv[c] - mean) * rstd * (double)g2[col] + (double)be2[col];
    }
  }
}

// -------- K4: LIF over T per (b,d) + residual add, fp32 out --------
__global__ __launch_bounds__(64) void k4_lif_res(
    const double* __restrict__ h2, const float* __restrict__ x,
    float* __restrict__ out, int row0)
{
  const int ci = blockIdx.x * 64 + threadIdx.x;
  const int b = ci >> 7, d = ci & 127;
  const double* p = h2 + (size_t)b * (T_*D_) + d;
  const size_t gbase = ((size_t)row0 + (size_t)b * T_) * D_ + d;
  double v = 0.0;
  #pragma unroll 8
  for (int t = 0; t < T_; ++t) {
    const double hv = p[(size_t)t * D_];
    const double hm = v + (hv - v) * 0.5;
    const bool s = (hm >= 1.0);
    v = s ? 0.0 : hm;
    out[gbase + (size_t)t * D_] = x[gbase + (size_t)t * D_] + (s ? 1.0f : 0.0f);
  }
}

extern "C" void kernel_launch(void* const* d_in, const int* in_sizes, int n_in,
                              void* d_out, int out_size, void* d_ws, size_t ws_size,
                              hipStream_t stream)
{
  const float* x   = (const float*)d_in[0];
  const float* W1  = (const float*)d_in[1];
  const float* b1  = (const float*)d_in[2];
  const float* g1  = (const float*)d_in[3];
  const float* be1 = (const float*)d_in[4];
  const float* W2  = (const float*)d_in[5];
  const float* b2  = (const float*)d_in[6];
  const float* g2  = (const float*)d_in[7];
  const float* be2 = (const float*)d_in[8];
  float* out = (float*)d_out;

  const size_t per_b = (size_t)T_*H_*sizeof(double) + (size_t)T_*H_ + (size_t)T_*D_*sizeof(double);
  int Bc = B_;
  while (Bc > 1 && (size_t)Bc * per_b > ws_size) Bc >>= 1;

  double*  h1 = (double*)d_ws;
  uint8_t* s1 = (uint8_t*)d_ws + (size_t)Bc*T_*H_*sizeof(double);
  double*  h2 = (double*)((uint8_t*)d_ws + (size_t)Bc*T_*H_*sizeof(double) + (size_t)Bc*T_*H_);

  const int nchunk = B_ / Bc;
  for (int c = 0; c < nchunk; ++c) {
    const int row0 = c * Bc * T_;
    k1_gemm_ln<<<dim3(Bc*4), dim3(256), 0, stream>>>(x, W1, b1, g1, be1, h1, row0);
    k2_lif   <<<dim3(Bc),   dim3(256), 0, stream>>>(h1, s1);
    k3_gemm_ln<<<dim3(Bc*4), dim3(256), 0, stream>>>(s1, W2, b2, g2, be2, h2);
    k4_lif_res<<<dim3(Bc*2), dim3(64),  0, stream>>>(h2, x, out, row0);
  }
}